// Round 7
// baseline (247.811 us; speedup 1.0000x reference)
//
#include <hip/hip_runtime.h>

#define KW 11
#define PAD 5
#define TW 32
#define TH 32
#define IW 42              // TW + KW - 1
#define IH 42
#define SROW 89            // s12 row stride (floats), ODD -> 2-way banks (free)
#define X2OFF 44           // x2 plane offset inside a row (read2 delta)
#define HROW 165           // h row stride = 5 planes x 33, ODD
#define HP1 33             // plane offsets: h1=0, h2=33, h11=66, h22=99, h12=132
#define IMH 512
#define IMW 512
#define NBLK 12288         // 16 x 16 x 48

__global__ __launch_bounds__(256, 3) void ssim_main(
    const float* __restrict__ img1, const float* __restrict__ img2,
    const float* __restrict__ window, float* __restrict__ partial)
{
    __shared__ float s12[IH * SROW];     // 14.9 KB
    __shared__ float hh[IH * HROW];      // 27.7 KB
    __shared__ float g[KW];
    __shared__ float wsum[4];

    const int t = threadIdx.x;

    // Separable 1D Gaussian = row-sums of the 2D window (columns sum to 1).
    if (t < KW) {
        float s = 0.f;
        for (int j = 0; j < KW; ++j) s += window[(t * KW + j) * 3];
        g[t] = s;
    }

    const int plane = blockIdx.z;
    const size_t base = (size_t)plane * IMH * IMW;
    const int ix0 = blockIdx.x * TW - PAD;
    const int iy0 = blockIdx.y * TH - PAD;

    // ---- Phase 0: stage inputs zero-padded (b32 writes, write2-pairable).
    for (int idx = t; idx < IH * IW; idx += 256) {
        int r = idx / IW, c = idx - r * IW;
        int gr = iy0 + r, gc = ix0 + c;
        float v1 = 0.f, v2 = 0.f;
        if (gr >= 0 && gr < IMH && gc >= 0 && gc < IMW) {
            size_t o = base + (size_t)gr * IMW + gc;
            v1 = img1[o];
            v2 = img2[o];
        }
        s12[r * SROW + c] = v1;
        s12[r * SROW + X2OFF + c] = v2;
    }
    __syncthreads();

    float wg[KW];
#pragma unroll
    for (int j = 0; j < KW; ++j) wg[j] = g[j];   // broadcast: conflict-free

    // ---- Phase 1: horizontal 11-tap; 168 tasks of 8 adjacent h-points.
    // 18 read2 + 20 write2 per 40 h-values. Streaming x-reads, fully-unrolled
    // constant-index accumulator arrays (promotes to VGPRs like R6's [4]).
    // Banks: addr = 89r + 8*oct + j; per fixed j exactly 2 lanes/bank (free).
    if (t < IH * 4) {
        const int r = t >> 2, oct = t & 3;
        const float* srow = &s12[r * SROW + oct * 8];
        float m1[8]  = {0, 0, 0, 0, 0, 0, 0, 0};
        float m2[8]  = {0, 0, 0, 0, 0, 0, 0, 0};
        float q11[8] = {0, 0, 0, 0, 0, 0, 0, 0};
        float q22[8] = {0, 0, 0, 0, 0, 0, 0, 0};
        float q12[8] = {0, 0, 0, 0, 0, 0, 0, 0};
#pragma unroll
        for (int j = 0; j < 18; ++j) {
            float x1 = srow[j];
            float x2 = srow[X2OFF + j];            // read2 pair, delta 44
            float s11 = x1 * x1;
            float s22 = x2 * x2;
            float sxy = x1 * x2;
#pragma unroll
            for (int p = 0; p < 8; ++p) {
                const int jj = j - p;
                if (jj >= 0 && jj < KW) {
                    float w = wg[jj];
                    m1[p]  += w * x1;
                    m2[p]  += w * x2;
                    q11[p] += w * s11;
                    q22[p] += w * s22;
                    q12[p] += w * sxy;
                }
            }
        }
        const int ho = r * HROW + oct * 8;
#pragma unroll
        for (int p = 0; p < 8; ++p) {              // adjacent p -> write2 pairs
            hh[ho + p]           = m1[p];
            hh[ho + HP1 + p]     = m2[p];
            hh[ho + 2 * HP1 + p] = q11[p];
            hh[ho + 3 * HP1 + p] = q22[p];
            hh[ho + 4 * HP1 + p] = q12[p];
        }
    }
    __syncthreads();

    // ---- Phase 2: vertical 11-tap; 128 tasks of 8 consecutive-row outputs.
    // 18 rows x 5 reads per 8 outputs = 11.25 reads/output (was 17.5).
    // Banks: 32 stride-1 cols x 2 row-groups per wave -> 2 lanes/bank (free).
    const float C1v = 0.0001f;
    const float C2v = 0.0009f;
    float lsum = 0.f;
    if (t < 128) {
        const int col = t & 31;
        const int rg = t >> 5;                     // rows rg*8 .. rg*8+7
        float am1[8]  = {0, 0, 0, 0, 0, 0, 0, 0};
        float am2[8]  = {0, 0, 0, 0, 0, 0, 0, 0};
        float s11a[8] = {0, 0, 0, 0, 0, 0, 0, 0};
        float s22a[8] = {0, 0, 0, 0, 0, 0, 0, 0};
        float sxa[8]  = {0, 0, 0, 0, 0, 0, 0, 0};
        const float* hp = &hh[(rg * 8) * HROW + col];
#pragma unroll
        for (int i = 0; i < 18; ++i) {
            float v1  = hp[i * HROW];              // read2 pairs (0,33),(66,99)
            float v2  = hp[i * HROW + HP1];
            float w11 = hp[i * HROW + 2 * HP1];
            float w22 = hp[i * HROW + 3 * HP1];
            float w12 = hp[i * HROW + 4 * HP1];
#pragma unroll
            for (int k = 0; k < 8; ++k) {
                const int j = i - k;
                if (j >= 0 && j < KW) {
                    float w = wg[j];
                    am1[k]  += w * v1;
                    am2[k]  += w * v2;
                    s11a[k] += w * w11;
                    s22a[k] += w * w22;
                    sxa[k]  += w * w12;
                }
            }
        }
#pragma unroll
        for (int k = 0; k < 8; ++k) {
            float mu1 = am1[k], mu2 = am2[k];
            float mu1sq = mu1 * mu1, mu2sq = mu2 * mu2, mu12 = mu1 * mu2;
            float sig1 = s11a[k] - mu1sq;
            float sig2 = s22a[k] - mu2sq;
            float sig12 = sxa[k] - mu12;
            float num = (2.f * mu12 + C1v) * (2.f * sig12 + C2v);
            float den = (mu1sq + mu2sq + C1v) * (sig1 + sig2 + C2v);
            float r = __builtin_amdgcn_rcpf(den);
            r = r * (2.f - den * r);               // Newton -> ~fp32 exact
            lsum += num * r;
        }
    }

    // ---- Reduction: wave shuffle -> cross-wave LDS -> plain per-block store.
#pragma unroll
    for (int off = 32; off > 0; off >>= 1) lsum += __shfl_down(lsum, off, 64);
    if ((t & 63) == 0) wsum[t >> 6] = lsum;
    __syncthreads();
    if (t == 0) {
        unsigned bid = (blockIdx.z * gridDim.y + blockIdx.y) * gridDim.x
                     + blockIdx.x;
        partial[bid] = wsum[0] + wsum[1] + wsum[2] + wsum[3];
    }
}

__global__ __launch_bounds__(256) void ssim_reduce(
    const float* __restrict__ partial, float* __restrict__ out, double inv_n)
{
    __shared__ double dsum[4];
    const int t = threadIdx.x;
    double s = 0.0;
    for (int i = t; i < NBLK; i += 256) s += (double)partial[i];
#pragma unroll
    for (int off = 32; off > 0; off >>= 1) s += __shfl_down(s, off, 64);
    if ((t & 63) == 0) dsum[t >> 6] = s;
    __syncthreads();
    if (t == 0) out[0] = (float)((dsum[0] + dsum[1] + dsum[2] + dsum[3]) * inv_n);
}

extern "C" void kernel_launch(void* const* d_in, const int* in_sizes, int n_in,
                              void* d_out, int out_size, void* d_ws, size_t ws_size,
                              hipStream_t stream) {
    const float* img1   = (const float*)d_in[0];
    const float* img2   = (const float*)d_in[1];
    const float* window = (const float*)d_in[2];
    float* out = (float*)d_out;
    float* partial = (float*)d_ws;               // 12288 floats = 48 KB

    const int nplanes = in_sizes[0] / (IMH * IMW);   // 48
    const long long total = (long long)in_sizes[0];

    dim3 grid(IMW / TW, IMH / TH, nplanes);      // 16 x 16 x 48 = 12288
    ssim_main<<<grid, 256, 0, stream>>>(img1, img2, window, partial);
    ssim_reduce<<<1, 256, 0, stream>>>(partial, out, 1.0 / (double)total);
}

// Round 8
// 188.151 us; speedup vs baseline: 1.3171x; 1.3171x over previous
//
#include <hip/hip_runtime.h>

#define KW 11
#define PAD 5
#define TW 32
#define TH 32
#define IW 42              // TW + KW - 1 (column span incl. halo)
#define VROW 215           // v-result row stride = 5 * 43, ODD
#define VP 43              // moment plane stride inside a row (read2 delta <=255)
#define IMH 512
#define IMW 512
#define NBLK 12288         // 16 x 16 x 48

// Layout of vertical-conv results: vv[r * VROW + m * VP + c],
// r in [0,32) output row, m in [0,5) moment, c in [0,42) column incl. halo.
// Bank check (phase B reads, lane = row(3b)<<3 | quad): 215r + 4q + const
// -> exactly 2 lanes per bank for every tap. Free.

__global__ __launch_bounds__(256, 4) void ssim_main(
    const float* __restrict__ img1, const float* __restrict__ img2,
    const float* __restrict__ window, float* __restrict__ partial)
{
    __shared__ float vv[TH * VROW];      // 27.5 KB
    __shared__ float g[KW];
    __shared__ float wsum[4];

    const int t = threadIdx.x;

    // Separable 1D Gaussian = row-sums of the 2D window (columns sum to 1).
    if (t < KW) {
        float s = 0.f;
        for (int j = 0; j < KW; ++j) s += window[(t * KW + j) * 3];
        g[t] = s;
    }
    __syncthreads();

    float wg[KW];
#pragma unroll
    for (int j = 0; j < KW; ++j) wg[j] = g[j];   // broadcast: conflict-free

    const int plane = blockIdx.z;
    const size_t base = (size_t)plane * IMH * IMW;
    const int ix0 = blockIdx.x * TW - PAD;
    const int iy0 = blockIdx.y * TH - PAD;

    // ---- Phase A: vertical 11-tap straight from GLOBAL (no staging pass).
    // 336 tasks = 42 cols x 8 row-groups of 4 output rows. Each task streams
    // 14 global rows (lane<->column: coalesced), accumulates 5 moments x 4
    // rows = 20 registers (spill-safe size), writes v-results to LDS.
    for (int task = t; task < IW * 8; task += 256) {
        const int c  = task % IW;
        const int rg = task / IW;
        const int gc = ix0 + c;
        const bool cvalid = (gc >= 0) && (gc < IMW);
        const int r0 = rg * 4;                    // first output row of group
        const int gr0 = iy0 + r0;                 // global row of tap i=0

        float m1[4]  = {0, 0, 0, 0};
        float m2[4]  = {0, 0, 0, 0};
        float q11[4] = {0, 0, 0, 0};
        float q22[4] = {0, 0, 0, 0};
        float q12[4] = {0, 0, 0, 0};
#pragma unroll
        for (int i = 0; i < 14; ++i) {
            const int gr = gr0 + i;
            const bool ok = cvalid && (gr >= 0) && (gr < IMH);
            const size_t o = base + (size_t)(ok ? gr : 0) * IMW + (ok ? gc : 0);
            float x1 = ok ? img1[o] : 0.f;
            float x2 = ok ? img2[o] : 0.f;
            float s11 = x1 * x1;
            float s22 = x2 * x2;
            float sxy = x1 * x2;
#pragma unroll
            for (int k = 0; k < 4; ++k) {
                const int j = i - k;
                if (j >= 0 && j < KW) {
                    float w = wg[j];
                    m1[k]  += w * x1;
                    m2[k]  += w * x2;
                    q11[k] += w * s11;
                    q22[k] += w * s22;
                    q12[k] += w * sxy;
                }
            }
        }
        const int vb = r0 * VROW + c;
#pragma unroll
        for (int k = 0; k < 4; ++k) {             // deltas 43/215: write2-pairable
            vv[vb + k * VROW]          = m1[k];
            vv[vb + k * VROW + VP]     = m2[k];
            vv[vb + k * VROW + 2 * VP] = q11[k];
            vv[vb + k * VROW + 3 * VP] = q22[k];
            vv[vb + k * VROW + 4 * VP] = q12[k];
        }
    }
    __syncthreads();

    // ---- Phase B: horizontal 11-tap + SSIM; 256 tasks of 4 adjacent cols.
    // 14 cols x 5 moments = 70 b32 reads (all offsets <=185: fully read2-
    // pairable) per 4 outputs. All 256 threads active.
    const float C1v = 0.0001f;
    const float C2v = 0.0009f;
    const int row = t >> 3;                       // 0..31
    const int qc = t & 7;                         // col quad 0..7
    const float* vp = &vv[row * VROW + qc * 4];
    float am1[4]  = {0, 0, 0, 0};
    float am2[4]  = {0, 0, 0, 0};
    float s11a[4] = {0, 0, 0, 0};
    float s22a[4] = {0, 0, 0, 0};
    float sxa[4]  = {0, 0, 0, 0};
#pragma unroll
    for (int cc = 0; cc < 14; ++cc) {
        float v1  = vp[cc];
        float v2  = vp[cc + VP];
        float w11 = vp[cc + 2 * VP];
        float w22 = vp[cc + 3 * VP];
        float w12 = vp[cc + 4 * VP];
#pragma unroll
        for (int k = 0; k < 4; ++k) {
            const int j = cc - k;
            if (j >= 0 && j < KW) {
                float w = wg[j];
                am1[k]  += w * v1;
                am2[k]  += w * v2;
                s11a[k] += w * w11;
                s22a[k] += w * w22;
                sxa[k]  += w * w12;
            }
        }
    }
    float lsum = 0.f;
#pragma unroll
    for (int k = 0; k < 4; ++k) {
        float mu1 = am1[k], mu2 = am2[k];
        float mu1sq = mu1 * mu1, mu2sq = mu2 * mu2, mu12 = mu1 * mu2;
        float sig1 = s11a[k] - mu1sq;
        float sig2 = s22a[k] - mu2sq;
        float sig12 = sxa[k] - mu12;
        float num = (2.f * mu12 + C1v) * (2.f * sig12 + C2v);
        float den = (mu1sq + mu2sq + C1v) * (sig1 + sig2 + C2v);
        float r = __builtin_amdgcn_rcpf(den);
        r = r * (2.f - den * r);                  // Newton -> ~fp32 exact
        lsum += num * r;
    }

    // ---- Reduction: wave shuffle -> cross-wave LDS -> plain per-block store.
#pragma unroll
    for (int off = 32; off > 0; off >>= 1) lsum += __shfl_down(lsum, off, 64);
    if ((t & 63) == 0) wsum[t >> 6] = lsum;
    __syncthreads();
    if (t == 0) {
        unsigned bid = (blockIdx.z * gridDim.y + blockIdx.y) * gridDim.x
                     + blockIdx.x;
        partial[bid] = wsum[0] + wsum[1] + wsum[2] + wsum[3];
    }
}

__global__ __launch_bounds__(256) void ssim_reduce(
    const float* __restrict__ partial, float* __restrict__ out, double inv_n)
{
    __shared__ double dsum[4];
    const int t = threadIdx.x;
    double s = 0.0;
    for (int i = t; i < NBLK; i += 256) s += (double)partial[i];
#pragma unroll
    for (int off = 32; off > 0; off >>= 1) s += __shfl_down(s, off, 64);
    if ((t & 63) == 0) dsum[t >> 6] = s;
    __syncthreads();
    if (t == 0) out[0] = (float)((dsum[0] + dsum[1] + dsum[2] + dsum[3]) * inv_n);
}

extern "C" void kernel_launch(void* const* d_in, const int* in_sizes, int n_in,
                              void* d_out, int out_size, void* d_ws, size_t ws_size,
                              hipStream_t stream) {
    const float* img1   = (const float*)d_in[0];
    const float* img2   = (const float*)d_in[1];
    const float* window = (const float*)d_in[2];
    float* out = (float*)d_out;
    float* partial = (float*)d_ws;               // 12288 floats = 48 KB

    const int nplanes = in_sizes[0] / (IMH * IMW);   // 48
    const long long total = (long long)in_sizes[0];

    dim3 grid(IMW / TW, IMH / TH, nplanes);      // 16 x 16 x 48 = 12288
    ssim_main<<<grid, 256, 0, stream>>>(img1, img2, window, partial);
    ssim_reduce<<<1, 256, 0, stream>>>(partial, out, 1.0 / (double)total);
}

// Round 9
// 178.283 us; speedup vs baseline: 1.3900x; 1.0554x over previous
//
#include <hip/hip_runtime.h>

#define KW 11
#define PAD 5
#define TW 32
#define TH 32
#define IW 42              // TW + KW - 1 (column span incl. halo)
#define VROW 215           // v-result row stride = 5 * 43, ODD (2-way banks: free)
#define VP 43              // moment plane stride inside a row
#define IMH 512
#define IMW 512
#define NBLK 12288         // 16 x 16 x 48

typedef float f2 __attribute__((ext_vector_type(2)));

// Vertical-conv results in LDS: vv[r*VROW + m*VP + c]; all accesses b32
// (proven conflict-free: odd strides -> exactly 2 lanes/bank per access).
// Packed-math pairing: (m1,m2) and (q11,q22) share weights -> v_pk_fma_f32.

template <bool EDGE>
__device__ __forceinline__ void phaseA(
    const float* __restrict__ img1, const float* __restrict__ img2,
    size_t base, int ix0, int iy0, int t, const float* wg,
    float* __restrict__ vv)
{
    for (int task = t; task < IW * 8; task += 256) {
        const int c  = task % IW;
        const int rg = task / IW;
        const int gc = ix0 + c;
        const int r0 = rg * 4;
        const int gr0 = iy0 + r0;

        f2 m12[4]  = {{0,0},{0,0},{0,0},{0,0}};   // (mu1, mu2) accumulators
        f2 qq[4]   = {{0,0},{0,0},{0,0},{0,0}};   // (x1^2, x2^2) accumulators
        float sx[4] = {0, 0, 0, 0};               // x1*x2 accumulator
        const bool cvalid = !EDGE || ((gc >= 0) && (gc < IMW));
#pragma unroll
        for (int i = 0; i < 14; ++i) {
            const int gr = gr0 + i;
            f2 x12;
            if (EDGE) {
                const bool ok = cvalid && (gr >= 0) && (gr < IMH);
                const size_t o = base + (size_t)(ok ? gr : 0) * IMW + (ok ? gc : 0);
                x12.x = ok ? img1[o] : 0.f;
                x12.y = ok ? img2[o] : 0.f;
            } else {
                const size_t o = base + (size_t)gr * IMW + gc;
                x12.x = img1[o];
                x12.y = img2[o];
            }
            f2 sq = x12 * x12;                    // packed mul
            float sxy = x12.x * x12.y;
#pragma unroll
            for (int k = 0; k < 4; ++k) {
                const int j = i - k;
                if (j >= 0 && j < KW) {
                    float w = wg[j];
                    f2 w2 = {w, w};
                    m12[k] += w2 * x12;           // v_pk_fma_f32
                    qq[k]  += w2 * sq;            // v_pk_fma_f32
                    sx[k]  += w * sxy;
                }
            }
        }
        const int vb = r0 * VROW + c;
#pragma unroll
        for (int k = 0; k < 4; ++k) {
            vv[vb + k * VROW]          = m12[k].x;
            vv[vb + k * VROW + VP]     = m12[k].y;
            vv[vb + k * VROW + 2 * VP] = qq[k].x;
            vv[vb + k * VROW + 3 * VP] = qq[k].y;
            vv[vb + k * VROW + 4 * VP] = sx[k];
        }
    }
}

__global__ __launch_bounds__(256, 4) void ssim_main(
    const float* __restrict__ img1, const float* __restrict__ img2,
    const float* __restrict__ window, float* __restrict__ partial)
{
    __shared__ float vv[TH * VROW];      // 27.5 KB
    __shared__ float g[KW];
    __shared__ float wsum[4];

    const int t = threadIdx.x;

    // Separable 1D Gaussian = row-sums of the 2D window (columns sum to 1).
    if (t < KW) {
        float s = 0.f;
        for (int j = 0; j < KW; ++j) s += window[(t * KW + j) * 3];
        g[t] = s;
    }
    __syncthreads();

    float wg[KW];
#pragma unroll
    for (int j = 0; j < KW; ++j) wg[j] = g[j];   // broadcast: conflict-free

    const int plane = blockIdx.z;
    const size_t base = (size_t)plane * IMH * IMW;
    const int ix0 = blockIdx.x * TW - PAD;
    const int iy0 = blockIdx.y * TH - PAD;

    // ---- Phase A: vertical 11-tap straight from global (lane<->col coalesced).
    // Interior blocks (76.6%) skip all bounds logic (block-uniform branch).
    const bool interior = (ix0 >= 0) && (ix0 + IW <= IMW) &&
                          (iy0 >= 0) && (iy0 + IW <= IMH);
    if (interior) phaseA<false>(img1, img2, base, ix0, iy0, t, wg, vv);
    else          phaseA<true >(img1, img2, base, ix0, iy0, t, wg, vv);
    __syncthreads();

    // ---- Phase B: horizontal 11-tap + SSIM; 4 adjacent cols per thread.
    const float C1v = 0.0001f;
    const float C2v = 0.0009f;
    const int row = t >> 3;                       // 0..31
    const int qc = t & 7;                         // col quad 0..7
    const float* vp = &vv[row * VROW + qc * 4];
    f2 am12[4] = {{0,0},{0,0},{0,0},{0,0}};
    f2 aqq[4]  = {{0,0},{0,0},{0,0},{0,0}};
    float asx[4] = {0, 0, 0, 0};
#pragma unroll
    for (int cc = 0; cc < 14; ++cc) {
        f2 v12 = {vp[cc],          vp[cc + VP]};
        f2 vqq = {vp[cc + 2 * VP], vp[cc + 3 * VP]};
        float vx = vp[cc + 4 * VP];
#pragma unroll
        for (int k = 0; k < 4; ++k) {
            const int j = cc - k;
            if (j >= 0 && j < KW) {
                float w = wg[j];
                f2 w2 = {w, w};
                am12[k] += w2 * v12;              // v_pk_fma_f32
                aqq[k]  += w2 * vqq;              // v_pk_fma_f32
                asx[k]  += w * vx;
            }
        }
    }
    float lsum = 0.f;
#pragma unroll
    for (int k = 0; k < 4; ++k) {
        float mu1 = am12[k].x, mu2 = am12[k].y;
        float mu1sq = mu1 * mu1, mu2sq = mu2 * mu2, mu12 = mu1 * mu2;
        float sig1 = aqq[k].x - mu1sq;
        float sig2 = aqq[k].y - mu2sq;
        float sig12 = asx[k] - mu12;
        float num = (2.f * mu12 + C1v) * (2.f * sig12 + C2v);
        float den = (mu1sq + mu2sq + C1v) * (sig1 + sig2 + C2v);
        float r = __builtin_amdgcn_rcpf(den);
        r = r * (2.f - den * r);                  // Newton -> ~fp32 exact
        lsum += num * r;
    }

    // ---- Reduction: wave shuffle -> cross-wave LDS -> plain per-block store.
#pragma unroll
    for (int off = 32; off > 0; off >>= 1) lsum += __shfl_down(lsum, off, 64);
    if ((t & 63) == 0) wsum[t >> 6] = lsum;
    __syncthreads();
    if (t == 0) {
        unsigned bid = (blockIdx.z * gridDim.y + blockIdx.y) * gridDim.x
                     + blockIdx.x;
        partial[bid] = wsum[0] + wsum[1] + wsum[2] + wsum[3];
    }
}

__global__ __launch_bounds__(256) void ssim_reduce(
    const float* __restrict__ partial, float* __restrict__ out, double inv_n)
{
    __shared__ double dsum[4];
    const int t = threadIdx.x;
    double s = 0.0;
    for (int i = t; i < NBLK; i += 256) s += (double)partial[i];
#pragma unroll
    for (int off = 32; off > 0; off >>= 1) s += __shfl_down(s, off, 64);
    if ((t & 63) == 0) dsum[t >> 6] = s;
    __syncthreads();
    if (t == 0) out[0] = (float)((dsum[0] + dsum[1] + dsum[2] + dsum[3]) * inv_n);
}

extern "C" void kernel_launch(void* const* d_in, const int* in_sizes, int n_in,
                              void* d_out, int out_size, void* d_ws, size_t ws_size,
                              hipStream_t stream) {
    const float* img1   = (const float*)d_in[0];
    const float* img2   = (const float*)d_in[1];
    const float* window = (const float*)d_in[2];
    float* out = (float*)d_out;
    float* partial = (float*)d_ws;               // 12288 floats = 48 KB

    const int nplanes = in_sizes[0] / (IMH * IMW);   // 48
    const long long total = (long long)in_sizes[0];

    dim3 grid(IMW / TW, IMH / TH, nplanes);      // 16 x 16 x 48 = 12288
    ssim_main<<<grid, 256, 0, stream>>>(img1, img2, window, partial);
    ssim_reduce<<<1, 256, 0, stream>>>(partial, out, 1.0 / (double)total);
}